// Round 2
// baseline (290.739 us; speedup 1.0000x reference)
//
#include <hip/hip_runtime.h>

// GCN 2-layer + edge MLP for SimpleModel_59545426592235.
// R6: packed u64 LDS aggregation, bid[] recorded at placement. Fixed-point
//     S1=2^18, S2=2^16, BIAS=2^23. Deterministic.
// R8: k_part was latency-bound (occupancy 12% = ~1 blk/CU, VALUBusy 4.7%,
//     HBM 8%). (a) CH 8192->4096: 782 blocks, LDS 72KB->40KB -> 4 blk/CU;
//     (b) NBMAX ping-pong scan (10 passes, 10 syncthreads) replaced with
//     shuffle-based block scan (4 elems/thread int4, __shfl_up over 64
//     lanes, 2 syncthreads); (c) col cached in regs across phases.

#define BLK 256
#define CH 4096            // edges per partition chunk
#define EPT (CH / BLK)     // 16 edges per thread
#define BSH 7              // 128 nodes per bucket
#define BSZ 128
#define NBMAX 1024         // max buckets (N <= 131072)
#define S1 262144.0f       // 2^18 conv1 scale
#define S2 65536.0f        // 2^16 conv2 scale
#define BIAS 8388608       // 2^23 low-field bias

// ---- per-chunk LDS histogram of col buckets -> global bucket counts
__global__ void k_hist(const int* __restrict__ col, int* __restrict__ gcount,
                       int E, int NB) {
    __shared__ int hist[NBMAX];
    int t = threadIdx.x;
    for (int b = t; b < NB; b += BLK) hist[b] = 0;
    __syncthreads();
    int e0 = blockIdx.x * CH;
    int cnt = min(CH, E - e0);
    for (int k = t; k < cnt; k += BLK)
        atomicAdd(&hist[col[e0 + k] >> BSH], 1);
    __syncthreads();
    for (int b = t; b < NB; b += BLK) {
        int h = hist[b];
        if (h) atomicAdd(&gcount[b], h);
    }
}

// ---- exclusive scan of bucket counts -> gbase[NB+1]; gcursor = gbase
__global__ void k_scan(const int* __restrict__ gcount, int* __restrict__ gbase,
                       int* __restrict__ gcursor, int NB) {
    __shared__ int sa[NBMAX], sb[NBMAX];
    int t = threadIdx.x;
    for (int i = t; i < NBMAX; i += BLK) sa[i] = (i < NB) ? gcount[i] : 0;
    __syncthreads();
    int *src = sa, *dst = sb;
    for (int off = 1; off < NBMAX; off <<= 1) {
        for (int i = t; i < NBMAX; i += BLK)
            dst[i] = src[i] + ((i >= off) ? src[i - off] : 0);
        __syncthreads();
        int* tmp = src; src = dst; dst = tmp;
    }
    for (int i = t; i < NB; i += BLK) {
        int ex = src[i] - gcount[i];
        gbase[i] = ex;
        gcursor[i] = ex;
    }
    if (t == 0) gbase[NB] = src[NB - 1];
}

// ---- partition: LDS counting sort of each chunk, coalesced run flush
__global__ void k_part(const int* __restrict__ row, const int* __restrict__ col,
                       int* __restrict__ gcursor, unsigned* __restrict__ part,
                       int E, int NB) {
    __shared__ __align__(16) int hist[NBMAX];
    __shared__ __align__(16) int lstart[NBMAX];
    __shared__ __align__(16) int lcur[NBMAX];
    __shared__ int gb[NBMAX];
    __shared__ unsigned sbuf[CH];
    __shared__ unsigned short bid[CH];
    __shared__ int wsum[BLK / 64];
    int t = threadIdx.x;
    int e0 = blockIdx.x * CH;
    int cnt = min(CH, E - e0);
    for (int i = t; i < NBMAX; i += BLK) hist[i] = 0;
    __syncthreads();
    // phase 1: histogram; cache col in registers
    int cv[EPT];
    #pragma unroll
    for (int i = 0; i < EPT; i++) {
        int k = t + i * BLK;
        if (k < cnt) {
            int c = col[e0 + k];
            cv[i] = c;
            atomicAdd(&hist[c >> BSH], 1);
        }
    }
    __syncthreads();
    // phase 2: exclusive scan of hist (4 buckets/thread, shuffle block scan)
    int i0 = 4 * t;
    int4 hv = reinterpret_cast<const int4*>(hist)[t];
    int h0 = hv.x, h1 = hv.y, h2 = hv.z, h3 = hv.w;
    int s1 = h0 + h1, s2 = s1 + h2, s3 = s2 + h3;
    int lane = t & 63, wid = t >> 6;
    int v = s3;
    #pragma unroll
    for (int off = 1; off < 64; off <<= 1) {
        int u = __shfl_up(v, off);
        if (lane >= off) v += u;
    }
    if (lane == 63) wsum[wid] = v;
    __syncthreads();
    int base = v - s3;               // exclusive within wave
    for (int w = 0; w < wid; w++) base += wsum[w];
    int ex0 = base, ex1 = base + h0, ex2 = base + s1, ex3 = base + s2;
    reinterpret_cast<int4*>(lstart)[t] = make_int4(ex0, ex1, ex2, ex3);
    reinterpret_cast<int4*>(lcur)[t]   = make_int4(ex0, ex1, ex2, ex3);
    gb[i0]     = h0 ? atomicAdd(&gcursor[i0],     h0) : 0;
    gb[i0 + 1] = h1 ? atomicAdd(&gcursor[i0 + 1], h1) : 0;
    gb[i0 + 2] = h2 ? atomicAdd(&gcursor[i0 + 2], h2) : 0;
    gb[i0 + 3] = h3 ? atomicAdd(&gcursor[i0 + 3], h3) : 0;
    __syncthreads();
    // phase 3: place chunk edges into LDS grouped by bucket; record bucket id
    #pragma unroll
    for (int i = 0; i < EPT; i++) {
        int k = t + i * BLK;
        if (k < cnt) {
            int c = cv[i];
            int r = row[e0 + k];
            int b = c >> BSH;
            int off = atomicAdd(&lcur[b], 1);
            sbuf[off] = ((unsigned)r << BSH) | (unsigned)(c & (BSZ - 1));
            bid[off] = (unsigned short)b;
        }
    }
    __syncthreads();
    // phase 4: flush, destination contiguous within each run
    #pragma unroll
    for (int i = 0; i < EPT; i++) {
        int j = t + i * BLK;
        if (j < cnt) {
            int b = bid[j];
            part[gb[b] + (j - lstart[b])] = sbuf[j];
        }
    }
}

// ---- per-bucket degree count -> deg, dinv, pi = x * dinv (fixed point)
__global__ void k_nodeA(const unsigned* __restrict__ part, const int* __restrict__ gbase,
                        const float2* __restrict__ x2, float* __restrict__ dinv,
                        int* __restrict__ degi, int2* __restrict__ pi, int N) {
    __shared__ int cnt[BSZ];
    int t = threadIdx.x;
    if (t < BSZ) cnt[t] = 0;
    __syncthreads();
    int b = blockIdx.x;
    int j0 = gbase[b], j1 = gbase[b + 1];
    for (int j = j0 + t; j < j1; j += BLK)
        atomicAdd(&cnt[part[j] & (BSZ - 1)], 1);
    __syncthreads();
    if (t < BSZ) {
        int node = (b << BSH) + t;
        if (node < N) {
            int dg = cnt[t];
            degi[node] = dg;
            float d = rsqrtf((float)(dg + 1));   // +1 self loop
            dinv[node] = d;
            float2 xv = x2[node];
            pi[node] = make_int2(__float2int_rn(xv.x * d * S1),
                                 __float2int_rn(xv.y * d * S1));
        }
    }
}

// ---- per-bucket conv1 aggregate (packed u64 LDS) -> h -> U, V, qi
__global__ void k_nodeB(const unsigned* __restrict__ part, const int* __restrict__ gbase,
                        const float* __restrict__ dinv, const int* __restrict__ degi,
                        const int2* __restrict__ pi,
                        const float* __restrict__ W1, const float* __restrict__ b1,
                        const float* __restrict__ W2, const float* __restrict__ We,
                        const float* __restrict__ be,
                        float4* __restrict__ U, float4* __restrict__ V,
                        int2* __restrict__ qi, int N) {
    __shared__ unsigned long long acc[BSZ];
    __shared__ float sW1[32], sb1[16], sW2[32], sWr[64], sWc[64], sbe[4];
    int t = threadIdx.x;
    if (t < BSZ) acc[t] = 0ull;
    if (t < 32) sW1[t] = W1[t];
    else if (t < 64) sW2[t - 32] = W2[t - 32];
    else if (t < 80) sb1[t - 64] = b1[t - 64];
    else if (t < 144) sWr[t - 80] = We[t - 80];          // We rows 0..15
    else if (t < 208) sWc[t - 144] = We[68 + (t - 144)]; // We rows 17..32
    else if (t < 212) sbe[t - 208] = be[t - 208];
    __syncthreads();
    int b = blockIdx.x;
    int j0 = gbase[b], j1 = gbase[b + 1];
    for (int j = j0 + t; j < j1; j += BLK) {
        unsigned w = part[j];
        int2 pv = pi[w >> BSH];
        int l = (int)(w & (BSZ - 1));
        unsigned long long val =
            ((unsigned long long)(unsigned)pv.x << 32) | (unsigned)(pv.y + BIAS);
        atomicAdd(&acc[l], val);
    }
    __syncthreads();
    if (t < BSZ) {
        int node = (b << BSH) + t;
        if (node < N) {
            unsigned long long a = acc[t];
            int sx = (int)(unsigned)(a >> 32);
            long long sy = (long long)(unsigned)(a & 0xffffffffull)
                         - (long long)degi[node] * BIAS;
            int2 ps = pi[node];  // self loop
            float d = dinv[node];
            float ax = (float)(ps.x + (long long)sx) * (1.0f / S1);
            float ay = (float)(ps.y + sy) * (1.0f / S1);
            float s0 = d * ax, s1 = d * ay;
            float u0 = sbe[0], u1 = sbe[1], u2 = sbe[2], u3 = sbe[3];
            float v0 = 0.f, v1 = 0.f, v2 = 0.f, v3 = 0.f;
            float w0 = 0.f, w1 = 0.f;
            #pragma unroll
            for (int jj = 0; jj < 16; jj++) {
                float hj = fmaf(s0, sW1[jj], fmaf(s1, sW1[16 + jj], sb1[jj]));
                u0 = fmaf(hj, sWr[4 * jj + 0], u0);
                u1 = fmaf(hj, sWr[4 * jj + 1], u1);
                u2 = fmaf(hj, sWr[4 * jj + 2], u2);
                u3 = fmaf(hj, sWr[4 * jj + 3], u3);
                v0 = fmaf(hj, sWc[4 * jj + 0], v0);
                v1 = fmaf(hj, sWc[4 * jj + 1], v1);
                v2 = fmaf(hj, sWc[4 * jj + 2], v2);
                v3 = fmaf(hj, sWc[4 * jj + 3], v3);
                w0 = fmaf(hj, sW2[2 * jj], w0);
                w1 = fmaf(hj, sW2[2 * jj + 1], w1);
            }
            U[node] = make_float4(u0, u1, u2, u3);
            V[node] = make_float4(v0, v1, v2, v3);
            float qx = w0 * d, qy = w1 * d;
            qi[node] = make_int2(__float2int_rn(qx * S2), __float2int_rn(qy * S2));
        }
    }
}

// ---- edge MLP: pure streaming, no atomics
__global__ void k_edge(const int* __restrict__ row, const int* __restrict__ col,
                       const float* __restrict__ ea, const float4* __restrict__ U,
                       const float4* __restrict__ V, const float* __restrict__ We,
                       float4* __restrict__ eout, int E) {
    __shared__ float sW16[4];
    int t = threadIdx.x;
    if (t < 4) sW16[t] = We[64 + t];   // We row 16 (edge_attr weights)
    __syncthreads();
    int e = blockIdx.x * BLK + t;
    if (e < E) {
        float4 u = U[row[e]];
        float4 v = V[col[e]];
        float av = ea[e];
        float a0 = u.x + fmaf(av, sW16[0], v.x);
        float a1 = u.y + fmaf(av, sW16[1], v.y);
        float a2 = u.z + fmaf(av, sW16[2], v.z);
        float a3 = u.w + fmaf(av, sW16[3], v.w);
        a0 = fmaxf(a0, 0.f); a1 = fmaxf(a1, 0.f);
        a2 = fmaxf(a2, 0.f); a3 = fmaxf(a3, 0.f);
        float m = fmaxf(fmaxf(a0, a1), fmaxf(a2, a3));
        float s = expf(a0 - m) + expf(a1 - m) + expf(a2 - m) + expf(a3 - m);
        float l = m + logf(s);
        eout[e] = make_float4(a0 - l, a1 - l, a2 - l, a3 - l);
    }
}

// ---- per-bucket conv2 aggregate (packed u64 LDS) -> node log_softmax
__global__ void k_nodeC(const unsigned* __restrict__ part, const int* __restrict__ gbase,
                        const float* __restrict__ dinv, const int* __restrict__ degi,
                        const int2* __restrict__ qi,
                        const float* __restrict__ b2, float2* __restrict__ outn, int N) {
    __shared__ unsigned long long acc[BSZ];
    int t = threadIdx.x;
    if (t < BSZ) acc[t] = 0ull;
    __syncthreads();
    int b = blockIdx.x;
    int j0 = gbase[b], j1 = gbase[b + 1];
    for (int j = j0 + t; j < j1; j += BLK) {
        unsigned w = part[j];
        int2 qv = qi[w >> BSH];
        int l = (int)(w & (BSZ - 1));
        unsigned long long val =
            ((unsigned long long)(unsigned)qv.x << 32) | (unsigned)(qv.y + BIAS);
        atomicAdd(&acc[l], val);
    }
    __syncthreads();
    if (t < BSZ) {
        int node = (b << BSH) + t;
        if (node < N) {
            unsigned long long a = acc[t];
            int sx = (int)(unsigned)(a >> 32);
            long long sy = (long long)(unsigned)(a & 0xffffffffull)
                         - (long long)degi[node] * BIAS;
            int2 qs = qi[node];  // self loop
            float d = dinv[node];
            float bx = (float)(qs.x + (long long)sx) * (1.0f / S2);
            float by = (float)(qs.y + sy) * (1.0f / S2);
            float o0 = fmaf(d, bx, b2[0]);
            float o1 = fmaf(d, by, b2[1]);
            float m = fmaxf(o0, o1);
            float l2 = m + logf(expf(o0 - m) + expf(o1 - m));
            outn[node] = make_float2(o0 - l2, o1 - l2);
        }
    }
}

extern "C" void kernel_launch(void* const* d_in, const int* in_sizes, int n_in,
                              void* d_out, int out_size, void* d_ws, size_t ws_size,
                              hipStream_t stream) {
    const float* x  = (const float*)d_in[0];
    const int*   ei = (const int*)d_in[1];
    const float* ea = (const float*)d_in[2];
    const float* W1 = (const float*)d_in[3];
    const float* b1 = (const float*)d_in[4];
    const float* We = (const float*)d_in[5];
    const float* be = (const float*)d_in[6];
    const float* W2 = (const float*)d_in[7];
    const float* b2 = (const float*)d_in[8];

    const int N = in_sizes[0] / 2;       // 100000
    const int E = in_sizes[2];           // 3200000
    const int* row = ei;
    const int* col = ei + E;
    const int NB  = (N + BSZ - 1) >> BSH;   // 782 buckets
    const int NCH = (E + CH - 1) / CH;      // 782 chunks

    float2* out_nodes = (float2*)d_out;                           // [N,2]
    float4* out_edges = (float4*)((float*)d_out + 2 * (size_t)N); // [E,4]

    // ws layout (bytes):
    char* ws = (char*)d_ws;
    int*      gcount  = (int*)     (ws + 0);         // NBMAX*4
    int*      gbase   = (int*)     (ws + 4096);      // (NBMAX+1)*4 (pad)
    int*      gcursor = (int*)     (ws + 12288);     // NBMAX*4
    float*    dinv    = (float*)   (ws + 16384);     // N*4
    int*      degi    = (int*)     (ws + 416384);    // N*4
    int2*     pi      = (int2*)    (ws + 816384);    // N*8
    int2*     qi      = (int2*)    (ws + 1616384);   // N*8
    float4*   U       = (float4*)  (ws + 2416384);   // N*16
    float4*   V       = (float4*)  (ws + 4016384);   // N*16
    unsigned* part    = (unsigned*)(ws + 5616384);   // E*4 -> 18.4 MB total

    hipMemsetAsync(gcount, 0, NBMAX * sizeof(int), stream);
    k_hist <<<NCH, BLK, 0, stream>>>(col, gcount, E, NB);
    k_scan <<<1,   BLK, 0, stream>>>(gcount, gbase, gcursor, NB);
    k_part <<<NCH, BLK, 0, stream>>>(row, col, gcursor, part, E, NB);
    k_nodeA<<<NB,  BLK, 0, stream>>>(part, gbase, (const float2*)x, dinv, degi, pi, N);
    k_nodeB<<<NB,  BLK, 0, stream>>>(part, gbase, dinv, degi, pi, W1, b1, W2, We, be, U, V, qi, N);
    k_edge <<<(E + BLK - 1) / BLK, BLK, 0, stream>>>(row, col, ea, U, V, We, out_edges, E);
    k_nodeC<<<NB,  BLK, 0, stream>>>(part, gbase, dinv, degi, qi, b2, out_nodes, N);
}

// Round 3
// 263.515 us; speedup vs baseline: 1.1033x; 1.1033x over previous
//
#include <hip/hip_runtime.h>

// GCN 2-layer + edge MLP for SimpleModel_59545426592235.
// R6: packed u64 LDS aggregation, bid[] recorded at placement. Fixed-point
//     S1=2^18, S2=2^16, BIAS=2^23. Deterministic.
// R8: shuffle block scan (2 barriers), col cached in regs.  CH 4096 regressed.
// R9: k_part/k_hist were serialized on contended global atomics: gcount and
//     gcursor are 3KB dense -> 16 counters share a 64B line; 306K(=NCH*NB)
//     atomics at ~6 G/s == the whole 53/99us. Fix: pad counters to one per
//     64B line (stride 16 ints); revert CH to 8192 (halves atomic count,
//     restores long flush runs / low write amplification). Padded arrays
//     alias the U/V regions (used strictly later) so ws stays 18.4MB.

#define BLK 256
#define CH 8192            // edges per partition chunk
#define EPT (CH / BLK)     // 32 edges per thread
#define BSH 7              // 128 nodes per bucket
#define BSZ 128
#define NBMAX 1024         // max buckets (N <= 131072)
#define PAD 16             // counter stride (ints) = one 64B line per counter
#define S1 262144.0f       // 2^18 conv1 scale
#define S2 65536.0f        // 2^16 conv2 scale
#define BIAS 8388608       // 2^23 low-field bias

// ---- per-chunk LDS histogram of col buckets -> global bucket counts (padded)
__global__ void k_hist(const int* __restrict__ col, int* __restrict__ gcount,
                       int E, int NB) {
    __shared__ int hist[NBMAX];
    int t = threadIdx.x;
    for (int b = t; b < NB; b += BLK) hist[b] = 0;
    __syncthreads();
    int e0 = blockIdx.x * CH;
    int cnt = min(CH, E - e0);
    for (int k = t; k < cnt; k += BLK)
        atomicAdd(&hist[col[e0 + k] >> BSH], 1);
    __syncthreads();
    for (int b = t; b < NB; b += BLK) {
        int h = hist[b];
        if (h) atomicAdd(&gcount[b * PAD], h);
    }
}

// ---- exclusive scan of padded counts -> gbase[NB+1] (dense); gcursor = gbase
__global__ void k_scan(const int* __restrict__ gcount, int* __restrict__ gbase,
                       int* __restrict__ gcursor, int NB) {
    __shared__ int sa[NBMAX], sb[NBMAX];
    int t = threadIdx.x;
    for (int i = t; i < NBMAX; i += BLK) sa[i] = (i < NB) ? gcount[i * PAD] : 0;
    __syncthreads();
    int *src = sa, *dst = sb;
    for (int off = 1; off < NBMAX; off <<= 1) {
        for (int i = t; i < NBMAX; i += BLK)
            dst[i] = src[i] + ((i >= off) ? src[i - off] : 0);
        __syncthreads();
        int* tmp = src; src = dst; dst = tmp;
    }
    for (int i = t; i < NB; i += BLK) {
        int ex = src[i] - ((i < NB) ? gcount[i * PAD] : 0);
        gbase[i] = ex;
        gcursor[i * PAD] = ex;
    }
    if (t == 0) gbase[NB] = src[NB - 1];
}

// ---- partition: LDS counting sort of each chunk, coalesced run flush
__global__ void k_part(const int* __restrict__ row, const int* __restrict__ col,
                       int* __restrict__ gcursor, unsigned* __restrict__ part,
                       int E, int NB) {
    __shared__ __align__(16) int hist[NBMAX];
    __shared__ __align__(16) int lstart[NBMAX];
    __shared__ __align__(16) int lcur[NBMAX];
    __shared__ int gb[NBMAX];
    __shared__ unsigned sbuf[CH];
    __shared__ unsigned short bid[CH];
    __shared__ int wsum[BLK / 64];
    int t = threadIdx.x;
    int e0 = blockIdx.x * CH;
    int cnt = min(CH, E - e0);
    for (int i = t; i < NBMAX; i += BLK) hist[i] = 0;
    __syncthreads();
    // phase 1: histogram; cache col in registers
    int cv[EPT];
    #pragma unroll
    for (int i = 0; i < EPT; i++) {
        int k = t + i * BLK;
        if (k < cnt) {
            int c = col[e0 + k];
            cv[i] = c;
            atomicAdd(&hist[c >> BSH], 1);
        }
    }
    __syncthreads();
    // phase 2: exclusive scan of hist (4 buckets/thread, shuffle block scan)
    int i0 = 4 * t;
    int4 hv = reinterpret_cast<const int4*>(hist)[t];
    int h0 = hv.x, h1 = hv.y, h2 = hv.z, h3 = hv.w;
    int s1 = h0 + h1, s2 = s1 + h2, s3 = s2 + h3;
    int lane = t & 63, wid = t >> 6;
    int v = s3;
    #pragma unroll
    for (int off = 1; off < 64; off <<= 1) {
        int u = __shfl_up(v, off);
        if (lane >= off) v += u;
    }
    if (lane == 63) wsum[wid] = v;
    __syncthreads();
    int base = v - s3;               // exclusive within wave
    for (int w = 0; w < wid; w++) base += wsum[w];
    int ex0 = base, ex1 = base + h0, ex2 = base + s1, ex3 = base + s2;
    reinterpret_cast<int4*>(lstart)[t] = make_int4(ex0, ex1, ex2, ex3);
    reinterpret_cast<int4*>(lcur)[t]   = make_int4(ex0, ex1, ex2, ex3);
    gb[i0]     = h0 ? atomicAdd(&gcursor[(i0)     * PAD], h0) : 0;
    gb[i0 + 1] = h1 ? atomicAdd(&gcursor[(i0 + 1) * PAD], h1) : 0;
    gb[i0 + 2] = h2 ? atomicAdd(&gcursor[(i0 + 2) * PAD], h2) : 0;
    gb[i0 + 3] = h3 ? atomicAdd(&gcursor[(i0 + 3) * PAD], h3) : 0;
    __syncthreads();
    // phase 3: place chunk edges into LDS grouped by bucket; record bucket id
    #pragma unroll
    for (int i = 0; i < EPT; i++) {
        int k = t + i * BLK;
        if (k < cnt) {
            int c = cv[i];
            int r = row[e0 + k];
            int b = c >> BSH;
            int off = atomicAdd(&lcur[b], 1);
            sbuf[off] = ((unsigned)r << BSH) | (unsigned)(c & (BSZ - 1));
            bid[off] = (unsigned short)b;
        }
    }
    __syncthreads();
    // phase 4: flush, destination contiguous within each run
    #pragma unroll
    for (int i = 0; i < EPT; i++) {
        int j = t + i * BLK;
        if (j < cnt) {
            int b = bid[j];
            part[gb[b] + (j - lstart[b])] = sbuf[j];
        }
    }
}

// ---- per-bucket degree count -> deg, dinv, pi = x * dinv (fixed point)
__global__ void k_nodeA(const unsigned* __restrict__ part, const int* __restrict__ gbase,
                        const float2* __restrict__ x2, float* __restrict__ dinv,
                        int* __restrict__ degi, int2* __restrict__ pi, int N) {
    __shared__ int cnt[BSZ];
    int t = threadIdx.x;
    if (t < BSZ) cnt[t] = 0;
    __syncthreads();
    int b = blockIdx.x;
    int j0 = gbase[b], j1 = gbase[b + 1];
    for (int j = j0 + t; j < j1; j += BLK)
        atomicAdd(&cnt[part[j] & (BSZ - 1)], 1);
    __syncthreads();
    if (t < BSZ) {
        int node = (b << BSH) + t;
        if (node < N) {
            int dg = cnt[t];
            degi[node] = dg;
            float d = rsqrtf((float)(dg + 1));   // +1 self loop
            dinv[node] = d;
            float2 xv = x2[node];
            pi[node] = make_int2(__float2int_rn(xv.x * d * S1),
                                 __float2int_rn(xv.y * d * S1));
        }
    }
}

// ---- per-bucket conv1 aggregate (packed u64 LDS) -> h -> U, V, qi
__global__ void k_nodeB(const unsigned* __restrict__ part, const int* __restrict__ gbase,
                        const float* __restrict__ dinv, const int* __restrict__ degi,
                        const int2* __restrict__ pi,
                        const float* __restrict__ W1, const float* __restrict__ b1,
                        const float* __restrict__ W2, const float* __restrict__ We,
                        const float* __restrict__ be,
                        float4* __restrict__ U, float4* __restrict__ V,
                        int2* __restrict__ qi, int N) {
    __shared__ unsigned long long acc[BSZ];
    __shared__ float sW1[32], sb1[16], sW2[32], sWr[64], sWc[64], sbe[4];
    int t = threadIdx.x;
    if (t < BSZ) acc[t] = 0ull;
    if (t < 32) sW1[t] = W1[t];
    else if (t < 64) sW2[t - 32] = W2[t - 32];
    else if (t < 80) sb1[t - 64] = b1[t - 64];
    else if (t < 144) sWr[t - 80] = We[t - 80];          // We rows 0..15
    else if (t < 208) sWc[t - 144] = We[68 + (t - 144)]; // We rows 17..32
    else if (t < 212) sbe[t - 208] = be[t - 208];
    __syncthreads();
    int b = blockIdx.x;
    int j0 = gbase[b], j1 = gbase[b + 1];
    for (int j = j0 + t; j < j1; j += BLK) {
        unsigned w = part[j];
        int2 pv = pi[w >> BSH];
        int l = (int)(w & (BSZ - 1));
        unsigned long long val =
            ((unsigned long long)(unsigned)pv.x << 32) | (unsigned)(pv.y + BIAS);
        atomicAdd(&acc[l], val);
    }
    __syncthreads();
    if (t < BSZ) {
        int node = (b << BSH) + t;
        if (node < N) {
            unsigned long long a = acc[t];
            int sx = (int)(unsigned)(a >> 32);
            long long sy = (long long)(unsigned)(a & 0xffffffffull)
                         - (long long)degi[node] * BIAS;
            int2 ps = pi[node];  // self loop
            float d = dinv[node];
            float ax = (float)(ps.x + (long long)sx) * (1.0f / S1);
            float ay = (float)(ps.y + sy) * (1.0f / S1);
            float s0 = d * ax, s1 = d * ay;
            float u0 = sbe[0], u1 = sbe[1], u2 = sbe[2], u3 = sbe[3];
            float v0 = 0.f, v1 = 0.f, v2 = 0.f, v3 = 0.f;
            float w0 = 0.f, w1 = 0.f;
            #pragma unroll
            for (int jj = 0; jj < 16; jj++) {
                float hj = fmaf(s0, sW1[jj], fmaf(s1, sW1[16 + jj], sb1[jj]));
                u0 = fmaf(hj, sWr[4 * jj + 0], u0);
                u1 = fmaf(hj, sWr[4 * jj + 1], u1);
                u2 = fmaf(hj, sWr[4 * jj + 2], u2);
                u3 = fmaf(hj, sWr[4 * jj + 3], u3);
                v0 = fmaf(hj, sWc[4 * jj + 0], v0);
                v1 = fmaf(hj, sWc[4 * jj + 1], v1);
                v2 = fmaf(hj, sWc[4 * jj + 2], v2);
                v3 = fmaf(hj, sWc[4 * jj + 3], v3);
                w0 = fmaf(hj, sW2[2 * jj], w0);
                w1 = fmaf(hj, sW2[2 * jj + 1], w1);
            }
            U[node] = make_float4(u0, u1, u2, u3);
            V[node] = make_float4(v0, v1, v2, v3);
            float qx = w0 * d, qy = w1 * d;
            qi[node] = make_int2(__float2int_rn(qx * S2), __float2int_rn(qy * S2));
        }
    }
}

// ---- edge MLP: pure streaming, no atomics
__global__ void k_edge(const int* __restrict__ row, const int* __restrict__ col,
                       const float* __restrict__ ea, const float4* __restrict__ U,
                       const float4* __restrict__ V, const float* __restrict__ We,
                       float4* __restrict__ eout, int E) {
    __shared__ float sW16[4];
    int t = threadIdx.x;
    if (t < 4) sW16[t] = We[64 + t];   // We row 16 (edge_attr weights)
    __syncthreads();
    int e = blockIdx.x * BLK + t;
    if (e < E) {
        float4 u = U[row[e]];
        float4 v = V[col[e]];
        float av = ea[e];
        float a0 = u.x + fmaf(av, sW16[0], v.x);
        float a1 = u.y + fmaf(av, sW16[1], v.y);
        float a2 = u.z + fmaf(av, sW16[2], v.z);
        float a3 = u.w + fmaf(av, sW16[3], v.w);
        a0 = fmaxf(a0, 0.f); a1 = fmaxf(a1, 0.f);
        a2 = fmaxf(a2, 0.f); a3 = fmaxf(a3, 0.f);
        float m = fmaxf(fmaxf(a0, a1), fmaxf(a2, a3));
        float s = expf(a0 - m) + expf(a1 - m) + expf(a2 - m) + expf(a3 - m);
        float l = m + logf(s);
        eout[e] = make_float4(a0 - l, a1 - l, a2 - l, a3 - l);
    }
}

// ---- per-bucket conv2 aggregate (packed u64 LDS) -> node log_softmax
__global__ void k_nodeC(const unsigned* __restrict__ part, const int* __restrict__ gbase,
                        const float* __restrict__ dinv, const int* __restrict__ degi,
                        const int2* __restrict__ qi,
                        const float* __restrict__ b2, float2* __restrict__ outn, int N) {
    __shared__ unsigned long long acc[BSZ];
    int t = threadIdx.x;
    if (t < BSZ) acc[t] = 0ull;
    __syncthreads();
    int b = blockIdx.x;
    int j0 = gbase[b], j1 = gbase[b + 1];
    for (int j = j0 + t; j < j1; j += BLK) {
        unsigned w = part[j];
        int2 qv = qi[w >> BSH];
        int l = (int)(w & (BSZ - 1));
        unsigned long long val =
            ((unsigned long long)(unsigned)qv.x << 32) | (unsigned)(qv.y + BIAS);
        atomicAdd(&acc[l], val);
    }
    __syncthreads();
    if (t < BSZ) {
        int node = (b << BSH) + t;
        if (node < N) {
            unsigned long long a = acc[t];
            int sx = (int)(unsigned)(a >> 32);
            long long sy = (long long)(unsigned)(a & 0xffffffffull)
                         - (long long)degi[node] * BIAS;
            int2 qs = qi[node];  // self loop
            float d = dinv[node];
            float bx = (float)(qs.x + (long long)sx) * (1.0f / S2);
            float by = (float)(qs.y + sy) * (1.0f / S2);
            float o0 = fmaf(d, bx, b2[0]);
            float o1 = fmaf(d, by, b2[1]);
            float m = fmaxf(o0, o1);
            float l2 = m + logf(expf(o0 - m) + expf(o1 - m));
            outn[node] = make_float2(o0 - l2, o1 - l2);
        }
    }
}

extern "C" void kernel_launch(void* const* d_in, const int* in_sizes, int n_in,
                              void* d_out, int out_size, void* d_ws, size_t ws_size,
                              hipStream_t stream) {
    const float* x  = (const float*)d_in[0];
    const int*   ei = (const int*)d_in[1];
    const float* ea = (const float*)d_in[2];
    const float* W1 = (const float*)d_in[3];
    const float* b1 = (const float*)d_in[4];
    const float* We = (const float*)d_in[5];
    const float* be = (const float*)d_in[6];
    const float* W2 = (const float*)d_in[7];
    const float* b2 = (const float*)d_in[8];

    const int N = in_sizes[0] / 2;       // 100000
    const int E = in_sizes[2];           // 3200000
    const int* row = ei;
    const int* col = ei + E;
    const int NB  = (N + BSZ - 1) >> BSH;   // 782 buckets
    const int NCH = (E + CH - 1) / CH;      // 391 chunks

    float2* out_nodes = (float2*)d_out;                           // [N,2]
    float4* out_edges = (float4*)((float*)d_out + 2 * (size_t)N); // [E,4]

    // ws layout (bytes). Padded counter arrays (64KB each) ALIAS the U/V
    // regions: gcount/gcursor are dead before k_nodeB writes U/V.
    char* ws = (char*)d_ws;
    int*      gbase   = (int*)     (ws + 0);         // (NBMAX+1)*4
    float*    dinv    = (float*)   (ws + 8192);      // N*4
    int*      degi    = (int*)     (ws + 408192);    // N*4
    int2*     pi      = (int2*)    (ws + 808192);    // N*8
    int2*     qi      = (int2*)    (ws + 1608192);   // N*8
    float4*   U       = (float4*)  (ws + 2408192);   // N*16
    float4*   V       = (float4*)  (ws + 4008192);   // N*16
    unsigned* part    = (unsigned*)(ws + 5608192);   // E*4 -> 18.4 MB total
    int*      gcount  = (int*)     (ws + 2408192);   // NBMAX*PAD*4 (aliases U)
    int*      gcursor = (int*)     (ws + 4008192);   // NBMAX*PAD*4 (aliases V)

    hipMemsetAsync(gcount, 0, NBMAX * PAD * sizeof(int), stream);
    k_hist <<<NCH, BLK, 0, stream>>>(col, gcount, E, NB);
    k_scan <<<1,   BLK, 0, stream>>>(gcount, gbase, gcursor, NB);
    k_part <<<NCH, BLK, 0, stream>>>(row, col, gcursor, part, E, NB);
    k_nodeA<<<NB,  BLK, 0, stream>>>(part, gbase, (const float2*)x, dinv, degi, pi, N);
    k_nodeB<<<NB,  BLK, 0, stream>>>(part, gbase, dinv, degi, pi, W1, b1, W2, We, be, U, V, qi, N);
    k_edge <<<(E + BLK - 1) / BLK, BLK, 0, stream>>>(row, col, ea, U, V, We, out_edges, E);
    k_nodeC<<<NB,  BLK, 0, stream>>>(part, gbase, dinv, degi, qi, b2, out_nodes, N);
}

// Round 4
// 240.798 us; speedup vs baseline: 1.2074x; 1.0943x over previous
//
#include <hip/hip_runtime.h>

// GCN 2-layer + edge MLP for SimpleModel_59545426592235.
// R6:  packed u64 LDS aggregation, bid[] recorded at placement. Fixed-point
//      S1=2^18, S2=2^16, BIAS=2^23. Deterministic.
// R8:  shuffle block scan; CH 4096 regressed (per-chunk overhead, not atomics).
// R9:  padded global counters -> NO change => atomic contention was never the
//      limiter. k_part is latency-bound at 4 waves/CU (12% occupancy).
// R10: attack the wave count: BLK 256->1024 (16 waves/block) for k_hist and
//      k_part; CH=12500 so grid = E/CH = 256 = exactly 1 block/CU, no tail.
//      LDS 91.4KB/block (sbuf 50000 + bid 25000 + 4x4KB tables + wsum), 1
//      block/CU -> occupancy 12%->~50%. Scan: 1 bucket/thread (NBMAX=1024).

#define BLK 256            // block size for node/edge kernels
#define BLKP 1024          // block size for k_hist / k_part (16 waves)
#define CH 12500           // edges per partition chunk: E = 256 * 12500 exactly
#define EPT 13             // ceil(CH / BLKP)
#define BSH 7              // 128 nodes per bucket
#define BSZ 128
#define NBMAX 1024         // max buckets (N <= 131072)
#define PAD 16             // counter stride (ints) = one 64B line per counter
#define S1 262144.0f       // 2^18 conv1 scale
#define S2 65536.0f        // 2^16 conv2 scale
#define BIAS 8388608       // 2^23 low-field bias

// ---- per-chunk LDS histogram of col buckets -> global bucket counts (padded)
__global__ __launch_bounds__(BLKP) void k_hist(const int* __restrict__ col,
                                               int* __restrict__ gcount,
                                               int E, int NB) {
    __shared__ int hist[NBMAX];
    int t = threadIdx.x;
    if (t < NBMAX) hist[t] = 0;
    __syncthreads();
    int e0 = blockIdx.x * CH;
    int cnt = min(CH, E - e0);
    #pragma unroll
    for (int i = 0; i < EPT; i++) {
        int k = t + i * BLKP;
        if (k < cnt) atomicAdd(&hist[col[e0 + k] >> BSH], 1);
    }
    __syncthreads();
    if (t < NB) {
        int h = hist[t];
        if (h) atomicAdd(&gcount[t * PAD], h);
    }
}

// ---- exclusive scan of padded counts -> gbase[NB+1] (dense); gcursor = gbase
__global__ void k_scan(const int* __restrict__ gcount, int* __restrict__ gbase,
                       int* __restrict__ gcursor, int NB) {
    __shared__ int sa[NBMAX], sb[NBMAX];
    int t = threadIdx.x;
    for (int i = t; i < NBMAX; i += BLK) sa[i] = (i < NB) ? gcount[i * PAD] : 0;
    __syncthreads();
    int *src = sa, *dst = sb;
    for (int off = 1; off < NBMAX; off <<= 1) {
        for (int i = t; i < NBMAX; i += BLK)
            dst[i] = src[i] + ((i >= off) ? src[i - off] : 0);
        __syncthreads();
        int* tmp = src; src = dst; dst = tmp;
    }
    for (int i = t; i < NB; i += BLK) {
        int ex = src[i] - gcount[i * PAD];
        gbase[i] = ex;
        gcursor[i * PAD] = ex;
    }
    if (t == 0) gbase[NB] = src[NB - 1];
}

// ---- partition: LDS counting sort of each chunk, coalesced run flush
__global__ __launch_bounds__(BLKP) void k_part(const int* __restrict__ row,
                                               const int* __restrict__ col,
                                               int* __restrict__ gcursor,
                                               unsigned* __restrict__ part,
                                               int E, int NB) {
    __shared__ int hist[NBMAX];
    __shared__ int lstart[NBMAX];
    __shared__ int lcur[NBMAX];
    __shared__ int gb[NBMAX];
    __shared__ unsigned sbuf[CH];
    __shared__ unsigned short bid[CH];
    __shared__ int wsum[BLKP / 64];
    int t = threadIdx.x;
    int e0 = blockIdx.x * CH;
    int cnt = min(CH, E - e0);
    if (t < NBMAX) hist[t] = 0;
    __syncthreads();
    // phase 1: histogram; cache col in registers
    int cv[EPT];
    #pragma unroll
    for (int i = 0; i < EPT; i++) {
        int k = t + i * BLKP;
        if (k < cnt) {
            int c = col[e0 + k];
            cv[i] = c;
            atomicAdd(&hist[c >> BSH], 1);
        }
    }
    __syncthreads();
    // phase 2: exclusive scan of hist (1 bucket/thread, shuffle block scan)
    int h = hist[t];
    int lane = t & 63, wid = t >> 6;
    int v = h;
    #pragma unroll
    for (int off = 1; off < 64; off <<= 1) {
        int u = __shfl_up(v, off);
        if (lane >= off) v += u;
    }
    if (lane == 63) wsum[wid] = v;
    __syncthreads();
    int base = v - h;                // exclusive within wave
    for (int w = 0; w < wid; w++) base += wsum[w];
    lstart[t] = base;
    lcur[t]   = base;
    gb[t] = h ? atomicAdd(&gcursor[t * PAD], h) : 0;
    __syncthreads();
    // phase 3: place chunk edges into LDS grouped by bucket; record bucket id
    #pragma unroll
    for (int i = 0; i < EPT; i++) {
        int k = t + i * BLKP;
        if (k < cnt) {
            int c = cv[i];
            int r = row[e0 + k];
            int b = c >> BSH;
            int off = atomicAdd(&lcur[b], 1);
            sbuf[off] = ((unsigned)r << BSH) | (unsigned)(c & (BSZ - 1));
            bid[off] = (unsigned short)b;
        }
    }
    __syncthreads();
    // phase 4: flush, destination contiguous within each run
    #pragma unroll
    for (int i = 0; i < EPT; i++) {
        int j = t + i * BLKP;
        if (j < cnt) {
            int b = bid[j];
            part[gb[b] + (j - lstart[b])] = sbuf[j];
        }
    }
}

// ---- per-bucket degree count -> deg, dinv, pi = x * dinv (fixed point)
__global__ void k_nodeA(const unsigned* __restrict__ part, const int* __restrict__ gbase,
                        const float2* __restrict__ x2, float* __restrict__ dinv,
                        int* __restrict__ degi, int2* __restrict__ pi, int N) {
    __shared__ int cnt[BSZ];
    int t = threadIdx.x;
    if (t < BSZ) cnt[t] = 0;
    __syncthreads();
    int b = blockIdx.x;
    int j0 = gbase[b], j1 = gbase[b + 1];
    for (int j = j0 + t; j < j1; j += BLK)
        atomicAdd(&cnt[part[j] & (BSZ - 1)], 1);
    __syncthreads();
    if (t < BSZ) {
        int node = (b << BSH) + t;
        if (node < N) {
            int dg = cnt[t];
            degi[node] = dg;
            float d = rsqrtf((float)(dg + 1));   // +1 self loop
            dinv[node] = d;
            float2 xv = x2[node];
            pi[node] = make_int2(__float2int_rn(xv.x * d * S1),
                                 __float2int_rn(xv.y * d * S1));
        }
    }
}

// ---- per-bucket conv1 aggregate (packed u64 LDS) -> h -> U, V, qi
__global__ void k_nodeB(const unsigned* __restrict__ part, const int* __restrict__ gbase,
                        const float* __restrict__ dinv, const int* __restrict__ degi,
                        const int2* __restrict__ pi,
                        const float* __restrict__ W1, const float* __restrict__ b1,
                        const float* __restrict__ W2, const float* __restrict__ We,
                        const float* __restrict__ be,
                        float4* __restrict__ U, float4* __restrict__ V,
                        int2* __restrict__ qi, int N) {
    __shared__ unsigned long long acc[BSZ];
    __shared__ float sW1[32], sb1[16], sW2[32], sWr[64], sWc[64], sbe[4];
    int t = threadIdx.x;
    if (t < BSZ) acc[t] = 0ull;
    if (t < 32) sW1[t] = W1[t];
    else if (t < 64) sW2[t - 32] = W2[t - 32];
    else if (t < 80) sb1[t - 64] = b1[t - 64];
    else if (t < 144) sWr[t - 80] = We[t - 80];          // We rows 0..15
    else if (t < 208) sWc[t - 144] = We[68 + (t - 144)]; // We rows 17..32
    else if (t < 212) sbe[t - 208] = be[t - 208];
    __syncthreads();
    int b = blockIdx.x;
    int j0 = gbase[b], j1 = gbase[b + 1];
    for (int j = j0 + t; j < j1; j += BLK) {
        unsigned w = part[j];
        int2 pv = pi[w >> BSH];
        int l = (int)(w & (BSZ - 1));
        unsigned long long val =
            ((unsigned long long)(unsigned)pv.x << 32) | (unsigned)(pv.y + BIAS);
        atomicAdd(&acc[l], val);
    }
    __syncthreads();
    if (t < BSZ) {
        int node = (b << BSH) + t;
        if (node < N) {
            unsigned long long a = acc[t];
            int sx = (int)(unsigned)(a >> 32);
            long long sy = (long long)(unsigned)(a & 0xffffffffull)
                         - (long long)degi[node] * BIAS;
            int2 ps = pi[node];  // self loop
            float d = dinv[node];
            float ax = (float)(ps.x + (long long)sx) * (1.0f / S1);
            float ay = (float)(ps.y + sy) * (1.0f / S1);
            float s0 = d * ax, s1 = d * ay;
            float u0 = sbe[0], u1 = sbe[1], u2 = sbe[2], u3 = sbe[3];
            float v0 = 0.f, v1 = 0.f, v2 = 0.f, v3 = 0.f;
            float w0 = 0.f, w1 = 0.f;
            #pragma unroll
            for (int jj = 0; jj < 16; jj++) {
                float hj = fmaf(s0, sW1[jj], fmaf(s1, sW1[16 + jj], sb1[jj]));
                u0 = fmaf(hj, sWr[4 * jj + 0], u0);
                u1 = fmaf(hj, sWr[4 * jj + 1], u1);
                u2 = fmaf(hj, sWr[4 * jj + 2], u2);
                u3 = fmaf(hj, sWr[4 * jj + 3], u3);
                v0 = fmaf(hj, sWc[4 * jj + 0], v0);
                v1 = fmaf(hj, sWc[4 * jj + 1], v1);
                v2 = fmaf(hj, sWc[4 * jj + 2], v2);
                v3 = fmaf(hj, sWc[4 * jj + 3], v3);
                w0 = fmaf(hj, sW2[2 * jj], w0);
                w1 = fmaf(hj, sW2[2 * jj + 1], w1);
            }
            U[node] = make_float4(u0, u1, u2, u3);
            V[node] = make_float4(v0, v1, v2, v3);
            float qx = w0 * d, qy = w1 * d;
            qi[node] = make_int2(__float2int_rn(qx * S2), __float2int_rn(qy * S2));
        }
    }
}

// ---- edge MLP: pure streaming, no atomics
__global__ void k_edge(const int* __restrict__ row, const int* __restrict__ col,
                       const float* __restrict__ ea, const float4* __restrict__ U,
                       const float4* __restrict__ V, const float* __restrict__ We,
                       float4* __restrict__ eout, int E) {
    __shared__ float sW16[4];
    int t = threadIdx.x;
    if (t < 4) sW16[t] = We[64 + t];   // We row 16 (edge_attr weights)
    __syncthreads();
    int e = blockIdx.x * BLK + t;
    if (e < E) {
        float4 u = U[row[e]];
        float4 v = V[col[e]];
        float av = ea[e];
        float a0 = u.x + fmaf(av, sW16[0], v.x);
        float a1 = u.y + fmaf(av, sW16[1], v.y);
        float a2 = u.z + fmaf(av, sW16[2], v.z);
        float a3 = u.w + fmaf(av, sW16[3], v.w);
        a0 = fmaxf(a0, 0.f); a1 = fmaxf(a1, 0.f);
        a2 = fmaxf(a2, 0.f); a3 = fmaxf(a3, 0.f);
        float m = fmaxf(fmaxf(a0, a1), fmaxf(a2, a3));
        float s = expf(a0 - m) + expf(a1 - m) + expf(a2 - m) + expf(a3 - m);
        float l = m + logf(s);
        eout[e] = make_float4(a0 - l, a1 - l, a2 - l, a3 - l);
    }
}

// ---- per-bucket conv2 aggregate (packed u64 LDS) -> node log_softmax
__global__ void k_nodeC(const unsigned* __restrict__ part, const int* __restrict__ gbase,
                        const float* __restrict__ dinv, const int* __restrict__ degi,
                        const int2* __restrict__ qi,
                        const float* __restrict__ b2, float2* __restrict__ outn, int N) {
    __shared__ unsigned long long acc[BSZ];
    int t = threadIdx.x;
    if (t < BSZ) acc[t] = 0ull;
    __syncthreads();
    int b = blockIdx.x;
    int j0 = gbase[b], j1 = gbase[b + 1];
    for (int j = j0 + t; j < j1; j += BLK) {
        unsigned w = part[j];
        int2 qv = qi[w >> BSH];
        int l = (int)(w & (BSZ - 1));
        unsigned long long val =
            ((unsigned long long)(unsigned)qv.x << 32) | (unsigned)(qv.y + BIAS);
        atomicAdd(&acc[l], val);
    }
    __syncthreads();
    if (t < BSZ) {
        int node = (b << BSH) + t;
        if (node < N) {
            unsigned long long a = acc[t];
            int sx = (int)(unsigned)(a >> 32);
            long long sy = (long long)(unsigned)(a & 0xffffffffull)
                         - (long long)degi[node] * BIAS;
            int2 qs = qi[node];  // self loop
            float d = dinv[node];
            float bx = (float)(qs.x + (long long)sx) * (1.0f / S2);
            float by = (float)(qs.y + sy) * (1.0f / S2);
            float o0 = fmaf(d, bx, b2[0]);
            float o1 = fmaf(d, by, b2[1]);
            float m = fmaxf(o0, o1);
            float l2 = m + logf(expf(o0 - m) + expf(o1 - m));
            outn[node] = make_float2(o0 - l2, o1 - l2);
        }
    }
}

extern "C" void kernel_launch(void* const* d_in, const int* in_sizes, int n_in,
                              void* d_out, int out_size, void* d_ws, size_t ws_size,
                              hipStream_t stream) {
    const float* x  = (const float*)d_in[0];
    const int*   ei = (const int*)d_in[1];
    const float* ea = (const float*)d_in[2];
    const float* W1 = (const float*)d_in[3];
    const float* b1 = (const float*)d_in[4];
    const float* We = (const float*)d_in[5];
    const float* be = (const float*)d_in[6];
    const float* W2 = (const float*)d_in[7];
    const float* b2 = (const float*)d_in[8];

    const int N = in_sizes[0] / 2;       // 100000
    const int E = in_sizes[2];           // 3200000
    const int* row = ei;
    const int* col = ei + E;
    const int NB  = (N + BSZ - 1) >> BSH;   // 782 buckets
    const int NCH = (E + CH - 1) / CH;      // 256 chunks

    float2* out_nodes = (float2*)d_out;                           // [N,2]
    float4* out_edges = (float4*)((float*)d_out + 2 * (size_t)N); // [E,4]

    // ws layout (bytes). Padded counter arrays (64KB each) ALIAS the U/V
    // regions: gcount/gcursor are dead before k_nodeB writes U/V.
    char* ws = (char*)d_ws;
    int*      gbase   = (int*)     (ws + 0);         // (NBMAX+1)*4
    float*    dinv    = (float*)   (ws + 8192);      // N*4
    int*      degi    = (int*)     (ws + 408192);    // N*4
    int2*     pi      = (int2*)    (ws + 808192);    // N*8
    int2*     qi      = (int2*)    (ws + 1608192);   // N*8
    float4*   U       = (float4*)  (ws + 2408192);   // N*16
    float4*   V       = (float4*)  (ws + 4008192);   // N*16
    unsigned* part    = (unsigned*)(ws + 5608192);   // E*4 -> 18.4 MB total
    int*      gcount  = (int*)     (ws + 2408192);   // NBMAX*PAD*4 (aliases U)
    int*      gcursor = (int*)     (ws + 4008192);   // NBMAX*PAD*4 (aliases V)

    hipMemsetAsync(gcount, 0, NBMAX * PAD * sizeof(int), stream);
    k_hist <<<NCH, BLKP, 0, stream>>>(col, gcount, E, NB);
    k_scan <<<1,   BLK,  0, stream>>>(gcount, gbase, gcursor, NB);
    k_part <<<NCH, BLKP, 0, stream>>>(row, col, gcursor, part, E, NB);
    k_nodeA<<<NB,  BLK,  0, stream>>>(part, gbase, (const float2*)x, dinv, degi, pi, N);
    k_nodeB<<<NB,  BLK,  0, stream>>>(part, gbase, dinv, degi, pi, W1, b1, W2, We, be, U, V, qi, N);
    k_edge <<<(E + BLK - 1) / BLK, BLK, 0, stream>>>(row, col, ea, U, V, We, out_edges, E);
    k_nodeC<<<NB,  BLK,  0, stream>>>(part, gbase, dinv, degi, qi, b2, out_nodes, N);
}